// Round 3
// baseline (641.321 us; speedup 1.0000x reference)
//
#include <hip/hip_runtime.h>
#include <hip/hip_bf16.h>
#include <stdint.h>

typedef unsigned short u16;
typedef __bf16 bf16x8 __attribute__((ext_vector_type(8)));
typedef float  f32x4  __attribute__((ext_vector_type(4)));
typedef float  fvec4  __attribute__((ext_vector_type(4)));

// problem dims
constexpr int NB = 64;           // batch
constexpr int NC = 256;          // cards
constexpr int NW = 256;          // words
constexpr int NE = 2048;         // E = GEMM K
constexpr int ND = 2048;         // D = GEMM N
constexpr int MROWS = NB * NW;   // 16384

// leader GEMM tiling (unchanged)
constexpr int BM = 128, BN = 128, BK = 64;
constexpr int KSPLIT = 4;
constexpr int KSLICE = NE / KSPLIT;  // 512

// big GEMM: 256x256 tile
constexpr int BM2 = 256, BN2 = 256;
constexpr int NT_K = NE / BK;        // 32 K-tiles
constexpr int NSLOT2 = ND / BN2;     // 8 partial slots (main path)
constexpr int NSLOT1 = ND / BN;      // 16 partial slots (fallback path)

// ws layout (bytes). part stays live through k_final.
constexpr size_t OFF_IDX  = 0;
constexpr size_t OFF_PART = 256;
constexpr size_t OFF_DOTP = 2097408;
constexpr size_t OFF_SSQP = 3145984;
constexpr size_t OFF_WW   = 4194560;
constexpr size_t NEED_MAIN = OFF_WW + (size_t)ND * NE * 2;   // ~12.6 MiB (WWb only)

__device__ __forceinline__ u16 f2bf(float f) {
    uint32_t u = __float_as_uint(f);
    u += 0x7fffu + ((u >> 16) & 1u);   // RNE
    return (u16)(u >> 16);
}

// ---------- fused: block 0 = argmax(y) -> idx; blocks 1.. = fp32->bf16 convert (WW only) ----------
__global__ void k_conv_argmax(const float* __restrict__ a, u16* __restrict__ da, int n4a,
                              const float* __restrict__ y, int* __restrict__ idx) {
    if (blockIdx.x == 0) {
        int t = threadIdx.x;
        int row = t >> 2, c = t & 3;
        float best = -3.4e38f; int bi = 0;
        for (int k = 0; k < 64; ++k) {
            int j = c + k * 4;
            float v = y[row * NC + j];
            if (v > best) { best = v; bi = j; }
        }
        #pragma unroll
        for (int off = 1; off <= 2; off <<= 1) {
            float ov = __shfl_xor(best, off, 64);
            int   oi = __shfl_xor(bi,   off, 64);
            if (ov > best || (ov == best && oi < bi)) { best = ov; bi = oi; }
        }
        if (c == 0) idx[row] = bi;
        return;
    }
    int i0 = (blockIdx.x - 1) * blockDim.x + threadIdx.x;
    int stride = (gridDim.x - 1) * blockDim.x;
    for (int i = i0; i < n4a; i += stride) {
        fvec4 v = __builtin_nontemporal_load(&((const fvec4*)a)[i]);
        ushort4 o = { f2bf(v.x), f2bf(v.y), f2bf(v.z), f2bf(v.w) };
        ((ushort4*)da)[i] = o;
    }
}

// ---------- split-K leader GEMM with fused gather ----------
__global__ __launch_bounds__(256) void k_gemm0(
    const float* __restrict__ ximg, const int* __restrict__ idx,
    const float* __restrict__ Wimg, float* __restrict__ part)
{
    __shared__ __align__(16) u16 sA[BM * BK];
    __shared__ __align__(16) u16 sB[BN * BK];
    __shared__ int s_idx[64];

    const int t  = threadIdx.x;
    const int l  = t & 63;
    const int wv = t >> 6;
    const int wm = wv >> 1, wn = wv & 1;

    const int nt = blockIdx.x >> 2, ks = blockIdx.x & 3;
    const int n0 = nt * BN;
    const int kbase = ks * KSLICE;

    if (t < 64) s_idx[t] = idx[t];

    f32x4 acc[4][4];
    #pragma unroll
    for (int i = 0; i < 4; ++i)
        #pragma unroll
        for (int j = 0; j < 4; ++j) acc[i][j] = (f32x4){0.f, 0.f, 0.f, 0.f};

    const int lr = l >> 3, lp = l & 7;

    for (int k0 = kbase; k0 < kbase + KSLICE; k0 += BK) {
        __syncthreads();
        #pragma unroll
        for (int i = 0; i < 4; ++i) {
            int r = wv * 32 + i * 8 + lr;
            int g = lp ^ (r & 7);
            if (r < 64) {
                const float* src = ximg + ((size_t)r * NC + s_idx[r]) * NE + k0 + g * 8;
                float4 v0 = *(const float4*)src;
                float4 v1 = *(const float4*)(src + 4);
                uint4 ov;
                ov.x = (uint32_t)f2bf(v0.x) | ((uint32_t)f2bf(v0.y) << 16);
                ov.y = (uint32_t)f2bf(v0.z) | ((uint32_t)f2bf(v0.w) << 16);
                ov.z = (uint32_t)f2bf(v1.x) | ((uint32_t)f2bf(v1.y) << 16);
                ov.w = (uint32_t)f2bf(v1.z) | ((uint32_t)f2bf(v1.w) << 16);
                *(uint4*)&sA[r * BK + lp * 8] = ov;
            } else {
                *(uint4*)&sA[r * BK + lp * 8] = (uint4){0, 0, 0, 0};
            }
        }
        #pragma unroll
        for (int i = 0; i < 4; ++i) {
            int r = wv * 32 + i * 8 + lr;
            int g = lp ^ (r & 7);
            const float* src = Wimg + (size_t)(n0 + r) * NE + k0 + g * 8;
            float4 v0 = *(const float4*)src;
            float4 v1 = *(const float4*)(src + 4);
            uint4 ov;
            ov.x = (uint32_t)f2bf(v0.x) | ((uint32_t)f2bf(v0.y) << 16);
            ov.y = (uint32_t)f2bf(v0.z) | ((uint32_t)f2bf(v0.w) << 16);
            ov.z = (uint32_t)f2bf(v1.x) | ((uint32_t)f2bf(v1.y) << 16);
            ov.w = (uint32_t)f2bf(v1.z) | ((uint32_t)f2bf(v1.w) << 16);
            *(uint4*)&sB[r * BK + lp * 8] = ov;
        }
        __syncthreads();

        #pragma unroll
        for (int kk = 0; kk < 2; ++kk) {
            bf16x8 af[4], bfr[4];
            #pragma unroll
            for (int mi = 0; mi < 4; ++mi) {
                int ra = wm * 64 + mi * 16 + (l & 15);
                int g  = kk * 4 + (l >> 4);
                int p  = g ^ (ra & 7);
                af[mi] = *(const bf16x8*)&sA[ra * BK + p * 8];
            }
            #pragma unroll
            for (int nj = 0; nj < 4; ++nj) {
                int rb = wn * 64 + nj * 16 + (l & 15);
                int g  = kk * 4 + (l >> 4);
                int p  = g ^ (rb & 7);
                bfr[nj] = *(const bf16x8*)&sB[rb * BK + p * 8];
            }
            #pragma unroll
            for (int mi = 0; mi < 4; ++mi)
                #pragma unroll
                for (int nj = 0; nj < 4; ++nj)
                    acc[mi][nj] = __builtin_amdgcn_mfma_f32_16x16x32_bf16(
                        af[mi], bfr[nj], acc[mi][nj], 0, 0, 0);
        }
    }

    if (wm == 0) {
        const int quad = l >> 4, lc = l & 15;
        #pragma unroll
        for (int mi = 0; mi < 4; ++mi)
            #pragma unroll
            for (int r = 0; r < 4; ++r) {
                int m = mi * 16 + quad * 4 + r;
                #pragma unroll
                for (int nj = 0; nj < 4; ++nj) {
                    int n = n0 + wn * 64 + nj * 16 + lc;
                    part[((size_t)ks * NB + m) * ND + n] = acc[mi][nj][r];
                }
            }
    }
}

// ---------- big GEMM main path: 256x256 tile, JIT 4-phase reads, 1-tile prefetch ----------
// A (xtxt) is fp32, converted in-kernel: issue 8 float4 loads of tile t+1 in ph1,
// convert + 4x ds_write_b128 in ph2 (compiler inserts the vmcnt wait).
// B (WWb) is bf16 via async global_load_lds.
// Race-freedom with ONE __syncthreads per K-tile:
//  * tile t lives in slot t&1; during tile t we stage tile t+1 into slot (t&1)^1,
//    whose previous contents (tile t-1) were fully consumed before the barrier that
//    opened tile t.
//  * the tile-end __syncthreads waits vmcnt(0)+lgkmcnt(0): all stages for t+1 landed,
//    all reads of slot t&1 retired.
#define GLD(sp, dp) __builtin_amdgcn_global_load_lds( \
    (const __attribute__((address_space(1))) void*)(sp), \
    (__attribute__((address_space(3))) void*)(dp), 16, 0, 0)

#define STAGE_B_HALF(h, kt, dstarr) do { \
    const u16* _s = Bsrc + (size_t)(h) * 128 * NE + (size_t)(kt) * BK; \
    u16* _d = &(dstarr)[(h) * 8192 + dst0]; \
    GLD(_s, _d); \
    GLD(_s + (size_t)64 * NE, _d + 4096); \
} while (0)

#define ISSUE_A(kt) do { if ((kt) < NT_K) { \
    _Pragma("unroll") for (int p = 0; p < 4; ++p) { \
        const float* _s = Asrc + (size_t)((p >> 1) * 128 + (p & 1) * 64) * NE + (size_t)(kt) * BK; \
        av0[p] = *(const float4*)_s; \
        av1[p] = *(const float4*)(_s + 4); \
    } } } while (0)

#define WRITE_A(S2, kt) do { if ((kt) < NT_K) { \
    _Pragma("unroll") for (int p = 0; p < 4; ++p) { \
        bf16x8 w; \
        w[0] = (__bf16)av0[p].x; w[1] = (__bf16)av0[p].y; \
        w[2] = (__bf16)av0[p].z; w[3] = (__bf16)av0[p].w; \
        w[4] = (__bf16)av1[p].x; w[5] = (__bf16)av1[p].y; \
        w[6] = (__bf16)av1[p].z; w[7] = (__bf16)av1[p].w; \
        *(bf16x8*)&lds[S2][0][(p >> 1) * 8192 + (p & 1) * 4096 + t * 8] = w; \
    } } } while (0)

#define RD_A(dst, mibase, pk) \
    _Pragma("unroll") for (int q = 0; q < 4; ++q) \
        dst[q] = *(const bf16x8*)&slA[arow + ((mibase) + q) * 1024 + (pk)];

#define RD_B(dst, pk) \
    _Pragma("unroll") for (int q = 0; q < 4; ++q) \
        dst[q] = *(const bf16x8*)&slB[brow + q * 1024 + (pk)];

#define MM(accbase, afr, bfr) \
    _Pragma("unroll") for (int q = 0; q < 4; ++q) \
        _Pragma("unroll") for (int nj = 0; nj < 4; ++nj) \
            acc[(accbase) + q][nj] = __builtin_amdgcn_mfma_f32_16x16x32_bf16( \
                afr[q], bfr[nj], acc[(accbase) + q][nj], 0, 0, 0);

#define TILE(S, tt) do { \
    const u16* slA = &lds[S][0][0]; \
    const u16* slB = &lds[S][1][0]; \
    bf16x8 af[4], bfr[4]; \
    float4 av0[4], av1[4]; \
    /* ph1: frags (mi0-3, kk0) + B(kk0); issue A fp32 loads of t+1; GLD B of t+1 */ \
    RD_A(af, 0, pk0); RD_B(bfr, pk0); \
    ISSUE_A((tt) + 1); \
    if ((tt) + 1 < NT_K) { \
        STAGE_B_HALF(0, (tt) + 1, lds[(S) ^ 1][1]); \
        STAGE_B_HALF(1, (tt) + 1, lds[(S) ^ 1][1]); \
    } \
    __builtin_amdgcn_s_setprio(1); MM(0, af, bfr); __builtin_amdgcn_s_setprio(0); \
    /* ph2: frags (mi4-7, kk0); MFMA then convert+write A of t+1 */ \
    RD_A(af, 4, pk0); \
    __builtin_amdgcn_s_setprio(1); MM(4, af, bfr); __builtin_amdgcn_s_setprio(0); \
    WRITE_A((S) ^ 1, (tt) + 1); \
    /* ph3: frags (mi0-3, kk1) + B(kk1) */ \
    RD_A(af, 0, pk1); RD_B(bfr, pk1); \
    __builtin_amdgcn_s_setprio(1); MM(0, af, bfr); __builtin_amdgcn_s_setprio(0); \
    /* ph4: frags (mi4-7, kk1) */ \
    RD_A(af, 4, pk1); \
    __builtin_amdgcn_s_setprio(1); MM(4, af, bfr); __builtin_amdgcn_s_setprio(0); \
    __syncthreads();   /* vmcnt(0)+lgkmcnt(0)+barrier: t+1 staged, slot S consumed */ \
} while (0)

__global__ __launch_bounds__(512, 2) void k_gemm1_8ph(
    const float* __restrict__ A, const u16* __restrict__ B,
    const float* __restrict__ bwrd, const float* __restrict__ bimg,
    const float* __restrict__ part,
    float* __restrict__ dotp, float* __restrict__ ssqp)
{
    __shared__ __align__(16) u16 lds[2][2][16384];   // [slot][A/B][256*64] = 128 KiB

    const int t  = threadIdx.x;          // 0..511
    const int l  = t & 63;
    const int wv = t >> 6;               // 0..7
    const int wm = wv >> 2;              // 0..1
    const int wn = wv & 3;               // 0..3

    const int mt = blockIdx.x >> 3;      // 0..63 == batch index (BM2 == NW)
    const int nt = blockIdx.x & 7;       // 0..7
    const int m0 = mt * BM2, n0 = nt * BN2;

    // staging: linear LDS dest, pre-swizzled global source (granule ^ row&7)
    const int r0 = t >> 3;                       // row within half, j=0
    const int ge = ((t & 7) ^ (r0 & 7)) * 8;     // swizzled src granule (elems)
    const float* Asrc = A + (size_t)(m0 + r0) * NE + ge;
    const u16*   Bsrc = B + (size_t)(n0 + r0) * NE + ge;
    const int dst0 = wv * 512;                   // wave-uniform LDS elem base (GLD)

    // fragment reads: p = (kk*4 + l>>4) ^ (l&7)
    const int lc16 = l & 15, khi = l >> 4, lx = l & 7;
    const int pk0 = (khi ^ lx) * 8;
    const int pk1 = ((4 + khi) ^ lx) * 8;
    const int arow = (wm * 128 + lc16) * 64;
    const int brow = (wn * 64 + lc16) * 64;

    f32x4 acc[8][4];
    #pragma unroll
    for (int i = 0; i < 8; ++i)
        #pragma unroll
        for (int j = 0; j < 4; ++j) acc[i][j] = (f32x4){0.f, 0.f, 0.f, 0.f};

    // prologue: stage tile0 into slot0 (A reg-converted, B via GLD), drain, go
    {
        float4 av0[4], av1[4];
        ISSUE_A(0);
        STAGE_B_HALF(0, 0, lds[0][1]);
        STAGE_B_HALF(1, 0, lds[0][1]);
        WRITE_A(0, 0);
    }
    __syncthreads();

    #pragma unroll 1
    for (int it = 0; it < NT_K / 2; ++it) {
        TILE(0, it * 2);
        TILE(1, it * 2 + 1);
    }

    // ---- epilogue: leader from split-K partials + bias; fused dot + sumsq
    const int quad = l >> 4, lc = l & 15;
    float bia[4], ldr[4];
    #pragma unroll
    for (int nj = 0; nj < 4; ++nj) {
        int n = n0 + wn * 64 + nj * 16 + lc;
        bia[nj] = bwrd[n];
        float ld = bimg[n];
        #pragma unroll
        for (int ks = 0; ks < KSPLIT; ++ks)
            ld += part[((size_t)ks * NB + mt) * ND + n];
        ldr[nj] = ld;
    }
    __syncthreads();                              // LDS reuse as reduction buffer
    float* sRed = (float*)&lds[0][0][0];          // pd: [256 rows][4 wn]; ps at +1024
    #pragma unroll
    for (int mi = 0; mi < 8; ++mi) {
        #pragma unroll
        for (int r = 0; r < 4; ++r) {
            float pd = 0.f, ps = 0.f;
            #pragma unroll
            for (int nj = 0; nj < 4; ++nj) {
                float v = acc[mi][nj][r] + bia[nj];
                pd += ldr[nj] * v;
                ps += v * v;
            }
            #pragma unroll
            for (int off = 1; off <= 8; off <<= 1) {
                pd += __shfl_xor(pd, off, 64);
                ps += __shfl_xor(ps, off, 64);
            }
            if (lc == 0) {
                int row = mi * 16 + quad * 4 + r;            // 0..127
                sRed[(wm * 128 + row) * 4 + wn]        = pd;
                sRed[1024 + (wm * 128 + row) * 4 + wn] = ps;
            }
        }
    }
    __syncthreads();
    if (t < 256) {
        int m = m0 + t;
        const fvec4* s4 = (const fvec4*)sRed;
        fvec4 vd = s4[t], vs = s4[256 + t];
        dotp[(size_t)nt * MROWS + m] = vd.x + vd.y + vd.z + vd.w;
        ssqp[(size_t)nt * MROWS + m] = vs.x + vs.y + vs.z + vs.w;
    }
}

#undef TILE
#undef MM
#undef RD_B
#undef RD_A
#undef WRITE_A
#undef ISSUE_A
#undef STAGE_B_HALF
#undef GLD

// ---------- fallback big GEMM (fp32 inputs, in-kernel convert; 128x128, 16 slots) ----------
__global__ __launch_bounds__(256) void k_gemm1_f32(
    const float* __restrict__ Av, const float* __restrict__ Bv,
    const float* __restrict__ bwrd, const float* __restrict__ bimg,
    const float* __restrict__ part,
    float* __restrict__ dotp, float* __restrict__ ssqp)
{
    __shared__ __align__(16) u16 sA[BM * BK];
    __shared__ __align__(16) u16 sB[BN * BK];

    const int t  = threadIdx.x;
    const int l  = t & 63;
    const int wv = t >> 6;
    const int wm = wv >> 1, wn = wv & 1;

    const int mt = blockIdx.x >> 4;
    const int nt = blockIdx.x & 15;
    const int m0 = mt * BM, n0 = nt * BN;

    f32x4 acc[4][4];
    #pragma unroll
    for (int i = 0; i < 4; ++i)
        #pragma unroll
        for (int jj = 0; jj < 4; ++jj) acc[i][jj] = (f32x4){0.f, 0.f, 0.f, 0.f};

    const int lr = l >> 3, lp = l & 7;

    for (int k0 = 0; k0 < NE; k0 += BK) {
        __syncthreads();
        #pragma unroll
        for (int i = 0; i < 4; ++i) {
            int r = wv * 32 + i * 8 + lr;
            int g = lp ^ (r & 7);
            const float* src = Av + (size_t)(m0 + r) * NE + k0 + g * 8;
            float4 v0 = *(const float4*)src;
            float4 v1 = *(const float4*)(src + 4);
            uint4 ov;
            ov.x = (uint32_t)f2bf(v0.x) | ((uint32_t)f2bf(v0.y) << 16);
            ov.y = (uint32_t)f2bf(v0.z) | ((uint32_t)f2bf(v0.w) << 16);
            ov.z = (uint32_t)f2bf(v1.x) | ((uint32_t)f2bf(v1.y) << 16);
            ov.w = (uint32_t)f2bf(v1.z) | ((uint32_t)f2bf(v1.w) << 16);
            *(uint4*)&sA[r * BK + lp * 8] = ov;
        }
        #pragma unroll
        for (int i = 0; i < 4; ++i) {
            int r = wv * 32 + i * 8 + lr;
            int g = lp ^ (r & 7);
            const float* src = Bv + (size_t)(n0 + r) * NE + k0 + g * 8;
            float4 v0 = *(const float4*)src;
            float4 v1 = *(const float4*)(src + 4);
            uint4 ov;
            ov.x = (uint32_t)f2bf(v0.x) | ((uint32_t)f2bf(v0.y) << 16);
            ov.y = (uint32_t)f2bf(v0.z) | ((uint32_t)f2bf(v0.w) << 16);
            ov.z = (uint32_t)f2bf(v1.x) | ((uint32_t)f2bf(v1.y) << 16);
            ov.w = (uint32_t)f2bf(v1.z) | ((uint32_t)f2bf(v1.w) << 16);
            *(uint4*)&sB[r * BK + lp * 8] = ov;
        }
        __syncthreads();

        #pragma unroll
        for (int kk = 0; kk < 2; ++kk) {
            bf16x8 af[4], bfr[4];
            #pragma unroll
            for (int mi = 0; mi < 4; ++mi) {
                int ra = wm * 64 + mi * 16 + (l & 15);
                int g  = kk * 4 + (l >> 4);
                int p  = g ^ (ra & 7);
                af[mi] = *(const bf16x8*)&sA[ra * BK + p * 8];
            }
            #pragma unroll
            for (int nj = 0; nj < 4; ++nj) {
                int rb = wn * 64 + nj * 16 + (l & 15);
                int g  = kk * 4 + (l >> 4);
                int p  = g ^ (rb & 7);
                bfr[nj] = *(const bf16x8*)&sB[rb * BK + p * 8];
            }
            #pragma unroll
            for (int mi = 0; mi < 4; ++mi)
                #pragma unroll
                for (int nj = 0; nj < 4; ++nj)
                    acc[mi][nj] = __builtin_amdgcn_mfma_f32_16x16x32_bf16(
                        af[mi], bfr[nj], acc[mi][nj], 0, 0, 0);
        }
    }

    const int quad = l >> 4, lc = l & 15;
    const int bidx = m0 >> 8;
    float bia[4], ldr[4];
    #pragma unroll
    for (int nj = 0; nj < 4; ++nj) {
        int n = n0 + wn * 64 + nj * 16 + lc;
        bia[nj] = bwrd[n];
        float ld = bimg[n];
        #pragma unroll
        for (int ks = 0; ks < KSPLIT; ++ks)
            ld += part[((size_t)ks * NB + bidx) * ND + n];
        ldr[nj] = ld;
    }
    __syncthreads();
    float* sRed = (float*)sA;
    #pragma unroll
    for (int mi = 0; mi < 4; ++mi) {
        #pragma unroll
        for (int r = 0; r < 4; ++r) {
            float pd = 0.f, ps = 0.f;
            #pragma unroll
            for (int nj = 0; nj < 4; ++nj) {
                float v = acc[mi][nj][r] + bia[nj];
                pd += ldr[nj] * v;
                ps += v * v;
            }
            #pragma unroll
            for (int off = 1; off <= 8; off <<= 1) {
                pd += __shfl_xor(pd, off, 64);
                ps += __shfl_xor(ps, off, 64);
            }
            if (lc == 0) {
                int lm = mi * 16 + quad * 4 + r;
                sRed[(wm * 2 + wn) * 64 + lm]       = pd;
                sRed[256 + (wm * 2 + wn) * 64 + lm] = ps;
            }
        }
    }
    __syncthreads();
    if (t < 128) {
        int wmm = t >> 6, lm = t & 63;
        int m = m0 + wmm * 64 + lm;
        dotp[(size_t)nt * MROWS + m] =
            sRed[(wmm * 2 + 0) * 64 + lm] + sRed[(wmm * 2 + 1) * 64 + lm];
        ssqp[(size_t)nt * MROWS + m] =
            sRed[256 + (wmm * 2 + 0) * 64 + lm] + sRed[256 + (wmm * 2 + 1) * 64 + lm];
    }
}

// ---------- ln2 from partials, reduce slots, logits + softmax ----------
__global__ void k_final(const float* __restrict__ part, const float* __restrict__ bimg,
                        const float* __restrict__ dotp, const float* __restrict__ ssqp,
                        float* __restrict__ out, int nslot) {
    int b = blockIdx.x, t = threadIdx.x;   // 256 threads
    __shared__ float rsum[4], redm[4], reds[4];
    float s2 = 0.f;
    #pragma unroll
    for (int i = 0; i < 8; ++i) {
        int d = i * 256 + t;
        float ld = bimg[d];
        #pragma unroll
        for (int ks = 0; ks < KSPLIT; ++ks)
            ld += part[((size_t)ks * NB + b) * ND + d];
        s2 += ld * ld;
    }
    for (int off = 1; off < 64; off <<= 1) s2 += __shfl_xor(s2, off, 64);
    if ((t & 63) == 0) rsum[t >> 6] = s2;
    __syncthreads();
    float ln2 = rsum[0] + rsum[1] + rsum[2] + rsum[3];

    int m = b * NW + t;
    float dt = 0.f, sq = 0.f;
    for (int s = 0; s < nslot; ++s) {
        dt += dotp[(size_t)s * MROWS + m];
        sq += ssqp[(size_t)s * MROWS + m];
    }
    float dn = sqrtf(ln2) * sqrtf(sq);
    float lg = dt / fmaxf(dn, 1e-8f);
    float mx = lg;
    for (int off = 1; off < 64; off <<= 1) mx = fmaxf(mx, __shfl_xor(mx, off, 64));
    int wvi = t >> 6;
    if ((t & 63) == 0) redm[wvi] = mx;
    __syncthreads();
    mx = fmaxf(fmaxf(redm[0], redm[1]), fmaxf(redm[2], redm[3]));
    float e = __expf(lg - mx);
    float s = e;
    for (int off = 1; off < 64; off <<= 1) s += __shfl_xor(s, off, 64);
    if ((t & 63) == 0) reds[wvi] = s;
    __syncthreads();
    s = reds[0] + reds[1] + reds[2] + reds[3];
    out[m] = e / s;
}

extern "C" void kernel_launch(void* const* d_in, const int* in_sizes, int n_in,
                              void* d_out, int out_size, void* d_ws, size_t ws_size,
                              hipStream_t stream) {
    const float* ximg = (const float*)d_in[0];
    const float* xtxt = (const float*)d_in[1];
    const float* y    = (const float*)d_in[2];
    const float* Wimg = (const float*)d_in[3];
    const float* bimg = (const float*)d_in[4];
    const float* Wwrd = (const float*)d_in[5];
    const float* bwrd = (const float*)d_in[6];
    float* out = (float*)d_out;

    char* ws = (char*)d_ws;
    int*   idx  = (int*)(ws + OFF_IDX);
    float* part = (float*)(ws + OFF_PART);
    float* dotp = (float*)(ws + OFF_DOTP);
    float* ssqp = (float*)(ws + OFF_SSQP);
    u16*   WWb  = (u16*)(ws + OFF_WW);

    const bool main_path = ws_size >= NEED_MAIN;

    if (main_path) {
        // WW bf16 convert (16.8 MB read) + argmax; xtxt converts inside gemm1
        k_conv_argmax<<<2049, 256, 0, stream>>>(Wwrd, WWb, ND * NE / 4, y, idx);
        k_gemm0<<<(ND / BN) * KSPLIT, 256, 0, stream>>>(ximg, idx, Wimg, part);
        k_gemm1_8ph<<<(MROWS / BM2) * (ND / BN2), 512, 0, stream>>>(
            xtxt, WWb, bwrd, bimg, part, dotp, ssqp);
        k_final<<<NB, 256, 0, stream>>>(part, bimg, dotp, ssqp, out, NSLOT2);
    } else {
        k_conv_argmax<<<1, 256, 0, stream>>>(nullptr, nullptr, 0, y, idx);
        k_gemm0<<<(ND / BN) * KSPLIT, 256, 0, stream>>>(ximg, idx, Wimg, part);
        k_gemm1_f32<<<(MROWS / BM) * (ND / BN), 256, 0, stream>>>(
            xtxt, Wwrd, bwrd, bimg, part, dotp, ssqp);
        k_final<<<NB, 256, 0, stream>>>(part, bimg, dotp, ssqp, out, NSLOT1);
    }
}

// Round 4
// 381.271 us; speedup vs baseline: 1.6821x; 1.6821x over previous
//
#include <hip/hip_runtime.h>
#include <hip/hip_bf16.h>
#include <stdint.h>

typedef unsigned short u16;
typedef __bf16 bf16x8 __attribute__((ext_vector_type(8)));
typedef float  f32x4  __attribute__((ext_vector_type(4)));
typedef float  fvec4  __attribute__((ext_vector_type(4)));

// problem dims
constexpr int NB = 64;           // batch
constexpr int NC = 256;          // cards
constexpr int NW = 256;          // words
constexpr int NE = 2048;         // E = GEMM K
constexpr int ND = 2048;         // D = GEMM N
constexpr int MROWS = NB * NW;   // 16384

// leader GEMM tiling
constexpr int BM = 128, BN = 128, BK = 64;
constexpr int KSPLIT = 4;
constexpr int KSLICE = NE / KSPLIT;  // 512

// big GEMM: 256x256 tile
constexpr int BM2 = 256, BN2 = 256;
constexpr int NT_K = NE / BK;        // 32 K-tiles
constexpr int NSLOT2 = ND / BN2;     // 8 partial slots (main path)
constexpr int NSLOT1 = ND / BN;      // 16 partial slots (fallback path)

// front kernel block roles
constexpr int G0_BLOCKS = 64;        // gemm0-role blocks
constexpr int CONV_BLOCKS = 2048;    // conversion-role blocks

// ws layout (bytes). part stays live through k_final.
constexpr size_t OFF_IDX  = 0;                         // unused now (kept for layout stability)
constexpr size_t OFF_PART = 256;
constexpr size_t OFF_DOTP = 2097408;
constexpr size_t OFF_SSQP = 3145984;
constexpr size_t OFF_WW   = 4194560;
constexpr size_t OFF_XT   = 12583168;
constexpr size_t NEED_FULL = OFF_XT + 67108864ull;     // ~76 MiB

__device__ __forceinline__ u16 f2bf(float f) {
    uint32_t u = __float_as_uint(f);
    u += 0x7fffu + ((u >> 16) & 1u);   // RNE
    return (u16)(u >> 16);
}

// ---------- fused front kernel ----------
// blocks [0, G0_BLOCKS): split-K leader GEMM (gemm0) with block-local argmax of y
// blocks [G0_BLOCKS, ..): grid-stride fp32->bf16 conversion of xtxt and Wwrd
// The two roles are independent (gemm0 reads ximg/Wimg fp32 directly), so the
// small gemm0 hides entirely under the conversion stream.
__global__ __launch_bounds__(256) void k_front(
    const float* __restrict__ ximg, const float* __restrict__ Wimg,
    const float* __restrict__ y, float* __restrict__ part,
    const float* __restrict__ xtxt, u16* __restrict__ XTb, int n4x,
    const float* __restrict__ Wwrd, u16* __restrict__ WWb, int n4w)
{
    if (blockIdx.x >= G0_BLOCKS) {
        // ---- conversion role ----
        int i0 = (int)(blockIdx.x - G0_BLOCKS) * 256 + threadIdx.x;
        int stride = (int)(gridDim.x - G0_BLOCKS) * 256;
        int n4 = n4x + n4w;
        for (int i = i0; i < n4; i += stride) {
            const fvec4* sp; ushort4* dp; int j;
            if (i < n4x) { sp = (const fvec4*)xtxt; dp = (ushort4*)XTb; j = i; }
            else         { sp = (const fvec4*)Wwrd; dp = (ushort4*)WWb; j = i - n4x; }
            fvec4 v = __builtin_nontemporal_load(&sp[j]);   // read-once stream
            ushort4 o = { f2bf(v.x), f2bf(v.y), f2bf(v.z), f2bf(v.w) };
            dp[j] = o;
        }
        return;
    }

    // ---- gemm0 role: part[ks][m][n] = sum_{k in slice} ximg[m, argmax(y[m]), k] * Wimg[n][k]
    __shared__ __align__(16) u16 sA[BM * BK];
    __shared__ __align__(16) u16 sB[BN * BK];
    __shared__ int s_idx[64];

    const int t  = threadIdx.x;
    const int l  = t & 63;
    const int wv = t >> 6;
    const int wm = wv >> 1, wn = wv & 1;

    const int nt = blockIdx.x >> 2, ks = blockIdx.x & 3;
    const int n0 = nt * BN;
    const int kbase = ks * KSLICE;

    {   // block-local argmax: 64 rows, 4 lanes per row scanning j = c, c+4, ... ascending
        int row = t >> 2, c = t & 3;
        float best = -3.4e38f; int bi = 0;
        for (int k = 0; k < 64; ++k) {
            int j = c + k * 4;
            float v = y[row * NC + j];
            if (v > best) { best = v; bi = j; }
        }
        #pragma unroll
        for (int off = 1; off <= 2; off <<= 1) {   // reduce within lane-quad; first-max tie-break
            float ov = __shfl_xor(best, off, 64);
            int   oi = __shfl_xor(bi,   off, 64);
            if (ov > best || (ov == best && oi < bi)) { best = ov; bi = oi; }
        }
        if (c == 0) s_idx[row] = bi;
    }

    f32x4 acc[4][4];
    #pragma unroll
    for (int i = 0; i < 4; ++i)
        #pragma unroll
        for (int j = 0; j < 4; ++j) acc[i][j] = (f32x4){0.f, 0.f, 0.f, 0.f};

    const int lr = l >> 3, lp = l & 7;

    for (int k0 = kbase; k0 < kbase + KSLICE; k0 += BK) {
        __syncthreads();   // also covers s_idx on first iteration
        #pragma unroll
        for (int i = 0; i < 4; ++i) {
            int r = wv * 32 + i * 8 + lr;
            int g = lp ^ (r & 7);
            if (r < 64) {
                const float* src = ximg + ((size_t)r * NC + s_idx[r]) * NE + k0 + g * 8;
                float4 v0 = *(const float4*)src;
                float4 v1 = *(const float4*)(src + 4);
                uint4 ov;
                ov.x = (uint32_t)f2bf(v0.x) | ((uint32_t)f2bf(v0.y) << 16);
                ov.y = (uint32_t)f2bf(v0.z) | ((uint32_t)f2bf(v0.w) << 16);
                ov.z = (uint32_t)f2bf(v1.x) | ((uint32_t)f2bf(v1.y) << 16);
                ov.w = (uint32_t)f2bf(v1.z) | ((uint32_t)f2bf(v1.w) << 16);
                *(uint4*)&sA[r * BK + lp * 8] = ov;
            } else {
                *(uint4*)&sA[r * BK + lp * 8] = (uint4){0, 0, 0, 0};
            }
        }
        #pragma unroll
        for (int i = 0; i < 4; ++i) {
            int r = wv * 32 + i * 8 + lr;
            int g = lp ^ (r & 7);
            const float* src = Wimg + (size_t)(n0 + r) * NE + k0 + g * 8;
            float4 v0 = *(const float4*)src;
            float4 v1 = *(const float4*)(src + 4);
            uint4 ov;
            ov.x = (uint32_t)f2bf(v0.x) | ((uint32_t)f2bf(v0.y) << 16);
            ov.y = (uint32_t)f2bf(v0.z) | ((uint32_t)f2bf(v0.w) << 16);
            ov.z = (uint32_t)f2bf(v1.x) | ((uint32_t)f2bf(v1.y) << 16);
            ov.w = (uint32_t)f2bf(v1.z) | ((uint32_t)f2bf(v1.w) << 16);
            *(uint4*)&sB[r * BK + lp * 8] = ov;
        }
        __syncthreads();

        #pragma unroll
        for (int kk = 0; kk < 2; ++kk) {
            bf16x8 af[4], bfr[4];
            #pragma unroll
            for (int mi = 0; mi < 4; ++mi) {
                int ra = wm * 64 + mi * 16 + (l & 15);
                int g  = kk * 4 + (l >> 4);
                int p  = g ^ (ra & 7);
                af[mi] = *(const bf16x8*)&sA[ra * BK + p * 8];
            }
            #pragma unroll
            for (int nj = 0; nj < 4; ++nj) {
                int rb = wn * 64 + nj * 16 + (l & 15);
                int g  = kk * 4 + (l >> 4);
                int p  = g ^ (rb & 7);
                bfr[nj] = *(const bf16x8*)&sB[rb * BK + p * 8];
            }
            #pragma unroll
            for (int mi = 0; mi < 4; ++mi)
                #pragma unroll
                for (int nj = 0; nj < 4; ++nj)
                    acc[mi][nj] = __builtin_amdgcn_mfma_f32_16x16x32_bf16(
                        af[mi], bfr[nj], acc[mi][nj], 0, 0, 0);
        }
    }

    if (wm == 0) {   // rows 0..63 live here
        const int quad = l >> 4, lc = l & 15;
        #pragma unroll
        for (int mi = 0; mi < 4; ++mi)
            #pragma unroll
            for (int r = 0; r < 4; ++r) {
                int m = mi * 16 + quad * 4 + r;     // 0..63
                #pragma unroll
                for (int nj = 0; nj < 4; ++nj) {
                    int n = n0 + wn * 64 + nj * 16 + lc;
                    part[((size_t)ks * NB + m) * ND + n] = acc[mi][nj][r];
                }
            }
    }
}

// ---------- big GEMM main path: 256x256 tile, JIT 4-phase reads, 1-tile prefetch ----------
// (proven R2 structure: 120 us, WRITE=1MB, no spill) + XCD-aware block swizzle.
// Race-freedom with ONE __syncthreads per K-tile:
//  * tile t lives in slot t&1; during tile t we stage tile t+1 into slot (t&1)^1,
//    whose previous contents (tile t-1) were fully consumed before the barrier that
//    opened tile t.
//  * the tile-end __syncthreads waits vmcnt(0)+lgkmcnt(0): all stages for t+1 landed,
//    all reads of slot t&1 retired. Stages issue in ph1/ph2 -> ~2-3 phases of MFMA
//    cover the load latency before the drain.
//  * fragments are read just-in-time per phase (<=8 live bf16x8) to stay within the
//    128-arch-VGPR budget (acc = 128 AGPR) -- no spills.
#define GLD(sp, dp) __builtin_amdgcn_global_load_lds( \
    (const __attribute__((address_space(1))) void*)(sp), \
    (__attribute__((address_space(3))) void*)(dp), 16, 0, 0)

#define STAGE_HALF(srcbase, h, kt, dstarr) do { \
    const u16* _s = (srcbase) + (size_t)(h) * 128 * NE + (size_t)(kt) * BK; \
    u16* _d = &(dstarr)[(h) * 8192 + dst0]; \
    GLD(_s, _d); \
    GLD(_s + (size_t)64 * NE, _d + 4096); \
} while (0)

#define RD_A(dst, mibase, pk) \
    _Pragma("unroll") for (int q = 0; q < 4; ++q) \
        dst[q] = *(const bf16x8*)&slA[arow + ((mibase) + q) * 1024 + (pk)];

#define RD_B(dst, pk) \
    _Pragma("unroll") for (int q = 0; q < 4; ++q) \
        dst[q] = *(const bf16x8*)&slB[brow + q * 1024 + (pk)];

#define MM(accbase, afr, bfr) \
    _Pragma("unroll") for (int q = 0; q < 4; ++q) \
        _Pragma("unroll") for (int nj = 0; nj < 4; ++nj) \
            acc[(accbase) + q][nj] = __builtin_amdgcn_mfma_f32_16x16x32_bf16( \
                afr[q], bfr[nj], acc[(accbase) + q][nj], 0, 0, 0);

#define TILE(S, tt) do { \
    const u16* slA = &lds[S][0][0]; \
    const u16* slB = &lds[S][1][0]; \
    bf16x8 af[4], bfr[4]; \
    /* ph1: frags (mi0-3, kk0) + B(kk0); stage A halves of t+1 into other slot */ \
    RD_A(af, 0, pk0); RD_B(bfr, pk0); \
    if ((tt) + 1 < NT_K) { \
        STAGE_HALF(Asrc, 0, (tt) + 1, lds[(S) ^ 1][0]); \
        STAGE_HALF(Asrc, 1, (tt) + 1, lds[(S) ^ 1][0]); \
    } \
    __builtin_amdgcn_s_setprio(1); MM(0, af, bfr); __builtin_amdgcn_s_setprio(0); \
    /* ph2: frags (mi4-7, kk0); stage B halves of t+1 */ \
    RD_A(af, 4, pk0); \
    if ((tt) + 1 < NT_K) { \
        STAGE_HALF(Bsrc, 0, (tt) + 1, lds[(S) ^ 1][1]); \
        STAGE_HALF(Bsrc, 1, (tt) + 1, lds[(S) ^ 1][1]); \
    } \
    __builtin_amdgcn_s_setprio(1); MM(4, af, bfr); __builtin_amdgcn_s_setprio(0); \
    /* ph3: frags (mi0-3, kk1) + B(kk1) */ \
    RD_A(af, 0, pk1); RD_B(bfr, pk1); \
    __builtin_amdgcn_s_setprio(1); MM(0, af, bfr); __builtin_amdgcn_s_setprio(0); \
    /* ph4: frags (mi4-7, kk1) */ \
    RD_A(af, 4, pk1); \
    __builtin_amdgcn_s_setprio(1); MM(4, af, bfr); __builtin_amdgcn_s_setprio(0); \
    __syncthreads();   /* vmcnt(0)+lgkmcnt(0)+barrier: t+1 staged, slot S consumed */ \
} while (0)

__global__ __launch_bounds__(512, 2) void k_gemm1_8ph(
    const u16* __restrict__ A, const u16* __restrict__ B,
    const float* __restrict__ bwrd, const float* __restrict__ bimg,
    const float* __restrict__ part,
    float* __restrict__ dotp, float* __restrict__ ssqp)
{
    __shared__ __align__(16) u16 lds[2][2][16384];   // [slot][A/B][256*64] = 128 KiB

    const int t  = threadIdx.x;          // 0..511
    const int l  = t & 63;
    const int wv = t >> 6;               // 0..7
    const int wm = wv >> 2;              // 0..1
    const int wn = wv & 3;               // 0..3

    // XCD-aware bijective swizzle: grid=512, 8 XCDs, 64 contiguous blocks per XCD.
    // Blocks sharing an A-panel (same mt) co-locate on one XCD's L2.
    const int bid = blockIdx.x;
    const int swz = (bid & 7) * 64 + (bid >> 3);
    const int mt = swz >> 3;             // 0..63 == batch index (BM2 == NW)
    const int nt = swz & 7;              // 0..7
    const int m0 = mt * BM2, n0 = nt * BN2;

    // staging: linear LDS dest, pre-swizzled global source (granule ^ row&7)
    const int r0 = t >> 3;                       // row within half, j=0
    const int ge = ((t & 7) ^ (r0 & 7)) * 8;     // swizzled src granule (u16 elems)
    const u16* Asrc = A + (size_t)(m0 + r0) * NE + ge;
    const u16* Bsrc = B + (size_t)(n0 + r0) * NE + ge;
    const int dst0 = wv * 512;                   // wave-uniform LDS elem base

    // fragment reads: p = (kk*4 + l>>4) ^ (l&7)
    const int lc16 = l & 15, khi = l >> 4, lx = l & 7;
    const int pk0 = (khi ^ lx) * 8;
    const int pk1 = ((4 + khi) ^ lx) * 8;
    const int arow = (wm * 128 + lc16) * 64;
    const int brow = (wn * 64 + lc16) * 64;

    f32x4 acc[8][4];
    #pragma unroll
    for (int i = 0; i < 8; ++i)
        #pragma unroll
        for (int j = 0; j < 4; ++j) acc[i][j] = (f32x4){0.f, 0.f, 0.f, 0.f};

    // prologue: stage tile0 into slot0, drain, go
    STAGE_HALF(Asrc, 0, 0, lds[0][0]);
    STAGE_HALF(Asrc, 1, 0, lds[0][0]);
    STAGE_HALF(Bsrc, 0, 0, lds[0][1]);
    STAGE_HALF(Bsrc, 1, 0, lds[0][1]);
    __syncthreads();

    #pragma unroll 1
    for (int it = 0; it < NT_K / 2; ++it) {
        TILE(0, it * 2);
        TILE(1, it * 2 + 1);
    }

    // ---- epilogue: leader from split-K partials + bias; fused dot + sumsq
    const int quad = l >> 4, lc = l & 15;
    float bia[4], ldr[4];
    #pragma unroll
    for (int nj = 0; nj < 4; ++nj) {
        int n = n0 + wn * 64 + nj * 16 + lc;
        bia[nj] = bwrd[n];
        float ld = bimg[n];
        #pragma unroll
        for (int ks = 0; ks < KSPLIT; ++ks)
            ld += part[((size_t)ks * NB + mt) * ND + n];
        ldr[nj] = ld;
    }
    __syncthreads();                              // LDS reuse as reduction buffer
    float* sRed = (float*)&lds[0][0][0];          // pd: [256 rows][4 wn]; ps at +1024
    #pragma unroll
    for (int mi = 0; mi < 8; ++mi) {
        #pragma unroll
        for (int r = 0; r < 4; ++r) {
            float pd = 0.f, ps = 0.f;
            #pragma unroll
            for (int nj = 0; nj < 4; ++nj) {
                float v = acc[mi][nj][r] + bia[nj];
                pd += ldr[nj] * v;
                ps += v * v;
            }
            #pragma unroll
            for (int off = 1; off <= 8; off <<= 1) {
                pd += __shfl_xor(pd, off, 64);
                ps += __shfl_xor(ps, off, 64);
            }
            if (lc == 0) {
                int row = mi * 16 + quad * 4 + r;            // 0..127
                sRed[(wm * 128 + row) * 4 + wn]        = pd;
                sRed[1024 + (wm * 128 + row) * 4 + wn] = ps;
            }
        }
    }
    __syncthreads();
    if (t < 256) {
        int m = m0 + t;
        const fvec4* s4 = (const fvec4*)sRed;
        fvec4 vd = s4[t], vs = s4[256 + t];
        dotp[(size_t)nt * MROWS + m] = vd.x + vd.y + vd.z + vd.w;
        ssqp[(size_t)nt * MROWS + m] = vs.x + vs.y + vs.z + vs.w;
    }
}

#undef TILE
#undef MM
#undef RD_B
#undef RD_A
#undef STAGE_HALF
#undef GLD

// ---------- fallback big GEMM (fp32 inputs, in-kernel convert; 128x128, 16 slots) ----------
__global__ __launch_bounds__(256) void k_gemm1_f32(
    const float* __restrict__ Av, const float* __restrict__ Bv,
    const float* __restrict__ bwrd, const float* __restrict__ bimg,
    const float* __restrict__ part,
    float* __restrict__ dotp, float* __restrict__ ssqp)
{
    __shared__ __align__(16) u16 sA[BM * BK];
    __shared__ __align__(16) u16 sB[BN * BK];

    const int t  = threadIdx.x;
    const int l  = t & 63;
    const int wv = t >> 6;
    const int wm = wv >> 1, wn = wv & 1;

    const int mt = blockIdx.x >> 4;
    const int nt = blockIdx.x & 15;
    const int m0 = mt * BM, n0 = nt * BN;

    f32x4 acc[4][4];
    #pragma unroll
    for (int i = 0; i < 4; ++i)
        #pragma unroll
        for (int jj = 0; jj < 4; ++jj) acc[i][jj] = (f32x4){0.f, 0.f, 0.f, 0.f};

    const int lr = l >> 3, lp = l & 7;

    for (int k0 = 0; k0 < NE; k0 += BK) {
        __syncthreads();
        #pragma unroll
        for (int i = 0; i < 4; ++i) {
            int r = wv * 32 + i * 8 + lr;
            int g = lp ^ (r & 7);
            const float* src = Av + (size_t)(m0 + r) * NE + k0 + g * 8;
            float4 v0 = *(const float4*)src;
            float4 v1 = *(const float4*)(src + 4);
            uint4 ov;
            ov.x = (uint32_t)f2bf(v0.x) | ((uint32_t)f2bf(v0.y) << 16);
            ov.y = (uint32_t)f2bf(v0.z) | ((uint32_t)f2bf(v0.w) << 16);
            ov.z = (uint32_t)f2bf(v1.x) | ((uint32_t)f2bf(v1.y) << 16);
            ov.w = (uint32_t)f2bf(v1.z) | ((uint32_t)f2bf(v1.w) << 16);
            *(uint4*)&sA[r * BK + lp * 8] = ov;
        }
        #pragma unroll
        for (int i = 0; i < 4; ++i) {
            int r = wv * 32 + i * 8 + lr;
            int g = lp ^ (r & 7);
            const float* src = Bv + (size_t)(n0 + r) * NE + k0 + g * 8;
            float4 v0 = *(const float4*)src;
            float4 v1 = *(const float4*)(src + 4);
            uint4 ov;
            ov.x = (uint32_t)f2bf(v0.x) | ((uint32_t)f2bf(v0.y) << 16);
            ov.y = (uint32_t)f2bf(v0.z) | ((uint32_t)f2bf(v0.w) << 16);
            ov.z = (uint32_t)f2bf(v1.x) | ((uint32_t)f2bf(v1.y) << 16);
            ov.w = (uint32_t)f2bf(v1.z) | ((uint32_t)f2bf(v1.w) << 16);
            *(uint4*)&sB[r * BK + lp * 8] = ov;
        }
        __syncthreads();

        #pragma unroll
        for (int kk = 0; kk < 2; ++kk) {
            bf16x8 af[4], bfr[4];
            #pragma unroll
            for (int mi = 0; mi < 4; ++mi) {
                int ra = wm * 64 + mi * 16 + (l & 15);
                int g  = kk * 4 + (l >> 4);
                int p  = g ^ (ra & 7);
                af[mi] = *(const bf16x8*)&sA[ra * BK + p * 8];
            }
            #pragma unroll
            for (int nj = 0; nj < 4; ++nj) {
                int rb = wn * 64 + nj * 16 + (l & 15);
                int g  = kk * 4 + (l >> 4);
                int p  = g ^ (rb & 7);
                bfr[nj] = *(const bf16x8*)&sB[rb * BK + p * 8];
            }
            #pragma unroll
            for (int mi = 0; mi < 4; ++mi)
                #pragma unroll
                for (int nj = 0; nj < 4; ++nj)
                    acc[mi][nj] = __builtin_amdgcn_mfma_f32_16x16x32_bf16(
                        af[mi], bfr[nj], acc[mi][nj], 0, 0, 0);
        }
    }

    const int quad = l >> 4, lc = l & 15;
    const int bidx = m0 >> 8;
    float bia[4], ldr[4];
    #pragma unroll
    for (int nj = 0; nj < 4; ++nj) {
        int n = n0 + wn * 64 + nj * 16 + lc;
        bia[nj] = bwrd[n];
        float ld = bimg[n];
        #pragma unroll
        for (int ks = 0; ks < KSPLIT; ++ks)
            ld += part[((size_t)ks * NB + bidx) * ND + n];
        ldr[nj] = ld;
    }
    __syncthreads();
    float* sRed = (float*)sA;
    #pragma unroll
    for (int mi = 0; mi < 4; ++mi) {
        #pragma unroll
        for (int r = 0; r < 4; ++r) {
            float pd = 0.f, ps = 0.f;
            #pragma unroll
            for (int nj = 0; nj < 4; ++nj) {
                float v = acc[mi][nj][r] + bia[nj];
                pd += ldr[nj] * v;
                ps += v * v;
            }
            #pragma unroll
            for (int off = 1; off <= 8; off <<= 1) {
                pd += __shfl_xor(pd, off, 64);
                ps += __shfl_xor(ps, off, 64);
            }
            if (lc == 0) {
                int lm = mi * 16 + quad * 4 + r;
                sRed[(wm * 2 + wn) * 64 + lm]       = pd;
                sRed[256 + (wm * 2 + wn) * 64 + lm] = ps;
            }
        }
    }
    __syncthreads();
    if (t < 128) {
        int wmm = t >> 6, lm = t & 63;
        int m = m0 + wmm * 64 + lm;
        dotp[(size_t)nt * MROWS + m] =
            sRed[(wmm * 2 + 0) * 64 + lm] + sRed[(wmm * 2 + 1) * 64 + lm];
        ssqp[(size_t)nt * MROWS + m] =
            sRed[256 + (wmm * 2 + 0) * 64 + lm] + sRed[256 + (wmm * 2 + 1) * 64 + lm];
    }
}

// ---------- ln2 from partials, reduce slots, logits + softmax ----------
__global__ void k_final(const float* __restrict__ part, const float* __restrict__ bimg,
                        const float* __restrict__ dotp, const float* __restrict__ ssqp,
                        float* __restrict__ out, int nslot) {
    int b = blockIdx.x, t = threadIdx.x;   // 256 threads
    __shared__ float rsum[4], redm[4], reds[4];
    float s2 = 0.f;
    #pragma unroll
    for (int i = 0; i < 8; ++i) {
        int d = i * 256 + t;
        float ld = bimg[d];
        #pragma unroll
        for (int ks = 0; ks < KSPLIT; ++ks)
            ld += part[((size_t)ks * NB + b) * ND + d];
        s2 += ld * ld;
    }
    for (int off = 1; off < 64; off <<= 1) s2 += __shfl_xor(s2, off, 64);
    if ((t & 63) == 0) rsum[t >> 6] = s2;
    __syncthreads();
    float ln2 = rsum[0] + rsum[1] + rsum[2] + rsum[3];

    int m = b * NW + t;
    float dt = 0.f, sq = 0.f;
    for (int s = 0; s < nslot; ++s) {
        dt += dotp[(size_t)s * MROWS + m];
        sq += ssqp[(size_t)s * MROWS + m];
    }
    float dn = sqrtf(ln2) * sqrtf(sq);
    float lg = dt / fmaxf(dn, 1e-8f);
    float mx = lg;
    for (int off = 1; off < 64; off <<= 1) mx = fmaxf(mx, __shfl_xor(mx, off, 64));
    int wvi = t >> 6;
    if ((t & 63) == 0) redm[wvi] = mx;
    __syncthreads();
    mx = fmaxf(fmaxf(redm[0], redm[1]), fmaxf(redm[2], redm[3]));
    float e = __expf(lg - mx);
    float s = e;
    for (int off = 1; off < 64; off <<= 1) s += __shfl_xor(s, off, 64);
    if ((t & 63) == 0) reds[wvi] = s;
    __syncthreads();
    s = reds[0] + reds[1] + reds[2] + reds[3];
    out[m] = e / s;
}

extern "C" void kernel_launch(void* const* d_in, const int* in_sizes, int n_in,
                              void* d_out, int out_size, void* d_ws, size_t ws_size,
                              hipStream_t stream) {
    const float* ximg = (const float*)d_in[0];
    const float* xtxt = (const float*)d_in[1];
    const float* y    = (const float*)d_in[2];
    const float* Wimg = (const float*)d_in[3];
    const float* bimg = (const float*)d_in[4];
    const float* Wwrd = (const float*)d_in[5];
    const float* bwrd = (const float*)d_in[6];
    float* out = (float*)d_out;

    char* ws = (char*)d_ws;
    float* part = (float*)(ws + OFF_PART);
    float* dotp = (float*)(ws + OFF_DOTP);
    float* ssqp = (float*)(ws + OFF_SSQP);
    u16*   WWb  = (u16*)(ws + OFF_WW);
    u16*   XTb  = (u16*)(ws + OFF_XT);

    const bool preconv = ws_size >= NEED_FULL;

    if (preconv) {
        // fused front: gemm0 (64 blocks, local argmax) overlaps xtxt+WW conversion
        k_front<<<G0_BLOCKS + CONV_BLOCKS, 256, 0, stream>>>(
            ximg, Wimg, y, part,
            xtxt, XTb, MROWS * NE / 4,
            Wwrd, WWb, ND * NE / 4);
        k_gemm1_8ph<<<(MROWS / BM2) * (ND / BN2), 512, 0, stream>>>(
            XTb, WWb, bwrd, bimg, part, dotp, ssqp);
        k_final<<<NB, 256, 0, stream>>>(part, bimg, dotp, ssqp, out, NSLOT2);
    } else {
        // fallback: gemm0-only front (no conversion blocks), fp32 big GEMM
        k_front<<<G0_BLOCKS, 256, 0, stream>>>(
            ximg, Wimg, y, part,
            nullptr, nullptr, 0,
            nullptr, nullptr, 0);
        k_gemm1_f32<<<(MROWS / BM) * (ND / BN), 256, 0, stream>>>(
            xtxt, Wwrd, bwrd, bimg, part, dotp, ssqp);
        k_final<<<NB, 256, 0, stream>>>(part, bimg, dotp, ssqp, out, NSLOT1);
    }
}